// Round 2
// baseline (136.947 us; speedup 1.0000x reference)
//
#include <hip/hip_runtime.h>
#include <math.h>

constexpr int NFFT = 256;          // OVERLAPS + STRIDES
constexpr int HOP  = 216;          // STRIDES
constexpr int PAD  = 20;           // M//2
constexpr int MT   = 41;           // FIR taps (unused name kept for clarity)
constexpr int LP   = NFFT + 2 * PAD; // 296

__device__ __forceinline__ void cmul(float& dr, float& di, float ar, float ai, float br, float bi) {
    dr = ar * br - ai * bi;
    di = ar * bi + ai * br;
}

// Block = 256 threads = 4 waves = 2 frames x 2 modes.
// Wave w: frame-local fl=w>>1, mode md=w&1. Lane l holds x[64q+l], q=0..3.
__global__ __launch_bounds__(256)
void eq_pbc_kernel(const float* __restrict__ x_real,
                   const float* __restrict__ x_imag,
                   const float* __restrict__ task_info,
                   const float* __restrict__ h_real,
                   const float* __restrict__ h_imag,
                   float* __restrict__ out,
                   int B, int L, int steps)
{
    // Phase A: intensity partials Ipart[fl][md][256] at Buf[(fl*2+md)*256]
    // Phase B (after barrier, aliased): Cr[fl][f] at Buf[fl*512+f], Ci at Buf[fl*512+256+f]
    __shared__ float Buf[2 * 2 * NFFT];
    __shared__ float Ipad[2][LP];

    const int tid = threadIdx.x;
    const int l   = tid & 63;
    const int w   = tid >> 6;
    const int fl  = w >> 1;
    const int md  = w & 1;
    const int G   = B * steps;
    int g = blockIdx.x * 2 + fl;
    const bool valid = (g < G);
    if (!valid) g = G - 1;
    const int b  = g / steps;
    const int s  = g - b * steps;
    const int l0 = HOP * s;

    const int br = (int)(__brev((unsigned)l) >> 26);   // 6-bit bit-reversal

    // ---- per-lane twiddles (shared by forward & inverse) ----
    constexpr float TWO_PI = 6.2831853071795864f;
    float t1i, t1r; __sincosf(-(TWO_PI / 256.0f) * (float)l, &t1i, &t1r);        // W256^l
    float t2r, t2i; cmul(t2r, t2i, t1r, t1i, t1r, t1i);                          // W256^2l
    float t3r, t3i; cmul(t3r, t3i, t2r, t2i, t1r, t1i);                          // W256^3l
    float w32i, w32r; __sincosf(-(TWO_PI / 64.0f) * (float)(l & 31), &w32i, &w32r);
    float w16i, w16r; __sincosf(-(TWO_PI / 32.0f) * (float)(l & 15), &w16i, &w16r);
    float w8i,  w8r;  __sincosf(-(TWO_PI / 16.0f) * (float)(l & 7),  &w8i,  &w8r);
    float w4i,  w4r;  __sincosf(-(TWO_PI / 8.0f)  * (float)(l & 3),  &w4i,  &w4r);
    const float w2r = (l & 1) ? 0.0f : 1.0f;
    const float w2i = (l & 1) ? -1.0f : 0.0f;

    // ---- load frame (this wave's mode): x[b][l0 + 64q + l][md] ----
    const float* xr_p = x_real + ((size_t)b * L + l0) * 2 + md;
    const float* xi_p = x_imag + ((size_t)b * L + l0) * 2 + md;
    float yr[4], yi[4];
    #pragma unroll
    for (int q = 0; q < 4; ++q) {
        yr[q] = xr_p[(q * 64 + l) * 2];
        yi[q] = xi_p[(q * 64 + l) * 2];
    }

    // ---- forward: radix-4 DIF first stage (in registers) ----
    {
        float Ar_ = yr[0] + yr[2], Ai_ = yi[0] + yi[2];
        float Br_ = yr[0] - yr[2], Bi_ = yi[0] - yi[2];
        float Cr_ = yr[1] + yr[3], Ci_ = yi[1] + yi[3];
        float Dr_ = yr[1] - yr[3], Di_ = yi[1] - yi[3];
        yr[0] = Ar_ + Cr_; yi[0] = Ai_ + Ci_;
        float u1r = Br_ + Di_, u1i = Bi_ - Dr_;   // B - iD
        float u2r = Ar_ - Cr_, u2i = Ai_ - Ci_;   // A - C
        float u3r = Br_ - Di_, u3i = Bi_ + Dr_;   // B + iD
        cmul(yr[1], yi[1], u1r, u1i, t1r, t1i);
        cmul(yr[2], yi[2], u2r, u2i, t2r, t2i);
        cmul(yr[3], yi[3], u3r, u3i, t3r, t3i);
    }

    // ---- forward: 4 cross-lane FFT-64 (DIF radix-2, no reorder -> bit-rev lanes) ----
    auto fwd_stage = [&](int h, float wr_, float wi_) {
        #pragma unroll
        for (int q = 0; q < 4; ++q) {
            float pr = __shfl_xor(yr[q], h);
            float pi = __shfl_xor(yi[q], h);
            float sr = yr[q] + pr, si = yi[q] + pi;   // low lane: a+b
            float dr = pr - yr[q], di = pi - yi[q];   // high lane: a-b
            float mr = dr * wr_ - di * wi_;
            float mi = dr * wi_ + di * wr_;
            bool hi = (l & h) != 0;
            yr[q] = hi ? mr : sr;
            yi[q] = hi ? mi : si;
        }
    };
    fwd_stage(32, w32r, w32i);
    fwd_stage(16, w16r, w16i);
    fwd_stage(8,  w8r,  w8i);
    fwd_stage(4,  w4r,  w4i);
    fwd_stage(2,  w2r,  w2i);
    fwd_stage(1,  1.0f, 0.0f);
    // lane l, reg q now holds X[4*br6(l) + q]

    // ---- intensity partial, scattered to natural order (one b128 per lane) ----
    {
        float4 iv;
        iv.x = yr[0] * yr[0] + yi[0] * yi[0];
        iv.y = yr[1] * yr[1] + yi[1] * yi[1];
        iv.z = yr[2] * yr[2] + yi[2] * yi[2];
        iv.w = yr[3] * yr[3] + yi[3] * yi[3];
        *(float4*)&Buf[(fl * 2 + md) * NFFT + 4 * br] = iv;
    }
    __syncthreads();

    // ---- combine modes + circular pad ----
    #pragma unroll
    for (int f2 = 0; f2 < 2; ++f2) {
        float v = Buf[f2 * 2 * NFFT + tid] + Buf[(f2 * 2 + 1) * NFFT + tid];
        Ipad[f2][PAD + tid] = v;
        if (tid < PAD)        Ipad[f2][NFFT + PAD + tid] = v;
        if (tid >= NFFT - PAD) Ipad[f2][tid - (NFFT - PAD)] = v;
    }
    __syncthreads();

    // ---- FIR: thread handles 2 adjacent bins of one frame; taps via scalar loads ----
    {
        const int ffl = tid >> 7;
        const int f0  = (tid & 127) * 2;
        const int gg  = blockIdx.x * 2 + ffl;
        const int bb  = ((gg < G) ? gg : (G - 1)) / steps;
        const float P = exp2f(task_info[4 * bb] * 0.33219280948873623f) * 0.5f; // 10^(ti/10)/Nm
        float pr0 = 0.f, pi0 = 0.f, pr1 = 0.f, pi1 = 0.f;
        const float2* Ip2 = (const float2*)&Ipad[ffl][f0];   // f0 even, 8B aligned
        float2 wv = Ip2[0];
        #pragma unroll
        for (int j = 0; j < 20; ++j) {
            float2 wn = Ip2[j + 1];
            float h0r = h_real[2 * j],     h0i = h_imag[2 * j];
            float h1r = h_real[2 * j + 1], h1i = h_imag[2 * j + 1];
            pr0 = fmaf(wv.x, h0r, pr0); pi0 = fmaf(wv.x, h0i, pi0);
            pr1 = fmaf(wv.y, h0r, pr1); pi1 = fmaf(wv.y, h0i, pi1);
            pr0 = fmaf(wv.y, h1r, pr0); pi0 = fmaf(wv.y, h1i, pi0);
            pr1 = fmaf(wn.x, h1r, pr1); pi1 = fmaf(wn.x, h1i, pi1);
            wv = wn;
        }
        float hLr = h_real[40], hLi = h_imag[40];
        pr0 = fmaf(wv.x, hLr, pr0); pi0 = fmaf(wv.x, hLi, pi0);
        pr1 = fmaf(wv.y, hLr, pr1); pi1 = fmaf(wv.y, hLi, pi1);
        // c = (1 - P*phi_i) + i*(P*phi_r)
        float2 crv = make_float2(1.0f - P * pi0, 1.0f - P * pi1);
        float2 civ = make_float2(P * pr0, P * pr1);
        *(float2*)&Buf[ffl * 2 * NFFT + f0]        = crv;
        *(float2*)&Buf[ffl * 2 * NFFT + NFFT + f0] = civ;
    }
    __syncthreads();

    // ---- modulate (gather c at f = 4*br+q: two b128 per lane) ----
    {
        float4 c4r = *(const float4*)&Buf[fl * 2 * NFFT + 4 * br];
        float4 c4i = *(const float4*)&Buf[fl * 2 * NFFT + NFFT + 4 * br];
        float crq[4] = {c4r.x, c4r.y, c4r.z, c4r.w};
        float ciq[4] = {c4i.x, c4i.y, c4i.z, c4i.w};
        #pragma unroll
        for (int q = 0; q < 4; ++q) {
            float xr_ = yr[q], xi_ = yi[q];
            yr[q] = xr_ * crq[q] - xi_ * ciq[q];
            yi[q] = xr_ * ciq[q] + xi_ * crq[q];
        }
    }

    // ---- inverse: mirrored cross-lane stages (conj twiddles), then inverse radix-4 ----
    auto inv_stage = [&](int h, float wr_, float wi_) {
        #pragma unroll
        for (int q = 0; q < 4; ++q) {
            float pr = __shfl_xor(yr[q], h);
            float pi = __shfl_xor(yi[q], h);
            bool hi = (l & h) != 0;
            float o1r = hi ? yr[q] : pr;
            float o1i = hi ? yi[q] : pi;
            float o0r = hi ? pr : yr[q];
            float o0i = hi ? pi : yi[q];
            float tr = o1r * wr_ + o1i * wi_;   // o1 * conj(w)
            float ti = o1i * wr_ - o1r * wi_;
            yr[q] = hi ? (o0r - tr) : (o0r + tr);
            yi[q] = hi ? (o0i - ti) : (o0i + ti);
        }
    };
    inv_stage(1,  1.0f, 0.0f);
    inv_stage(2,  w2r,  w2i);
    inv_stage(4,  w4r,  w4i);
    inv_stage(8,  w8r,  w8i);
    inv_stage(16, w16r, w16i);
    inv_stage(32, w32r, w32i);
    {
        float z1r, z1i, z2r, z2i, z3r, z3i;
        cmul(z1r, z1i, yr[1], yi[1], t1r, -t1i);
        cmul(z2r, z2i, yr[2], yi[2], t2r, -t2i);
        cmul(z3r, z3i, yr[3], yi[3], t3r, -t3i);
        float Ar_ = yr[0] + z2r, Ai_ = yi[0] + z2i;
        float Cr_ = yr[0] - z2r, Ci_ = yi[0] - z2i;
        float Br_ = z1r + z3r,  Bi_ = z1i + z3i;
        float Dpr = z3r - z1r,  Dpi = z3i - z1i;   // 2iD
        float Dr_ = Dpi, Di_ = -Dpr;               // D = -i*(2iD) -> 2D (scale folded)
        yr[0] = Ar_ + Br_; yi[0] = Ai_ + Bi_;
        yr[2] = Ar_ - Br_; yi[2] = Ai_ - Bi_;
        yr[1] = Cr_ + Dr_; yi[1] = Ci_ + Di_;
        yr[3] = Cr_ - Dr_; yi[3] = Ci_ - Di_;
    }
    // lane l, reg q holds 256 * y[64q + l]  (natural time order)

    // ---- OLA + wsum + crop ----
    if (valid) {
        const int Lout = L - 2 * PAD;
        float* obase = out + (size_t)b * Lout * 4 + md * 2;
        #pragma unroll
        for (int q = 0; q < 4; ++q) {
            int n  = q * 64 + l;
            int la = l0 + n;
            if (la < PAD || la >= L - PAD) continue;
            bool ov = (n < NFFT - HOP && s > 0) || (n >= HOP && s + 1 < steps);
            float sc = (ov ? 0.5f : 1.0f) * (1.0f / 256.0f);
            float vr = yr[q] * sc, vi = yi[q] * sc;
            float* p = obase + (size_t)(la - PAD) * 4;
            if (ov) { atomicAdd(p, vr); atomicAdd(p + 1, vi); }
            else    { *(float2*)p = make_float2(vr, vi); }
        }
    }
}

extern "C" void kernel_launch(void* const* d_in, const int* in_sizes, int n_in,
                              void* d_out, int out_size, void* d_ws, size_t ws_size,
                              hipStream_t stream) {
    const float* x_real    = (const float*)d_in[0];
    const float* x_imag    = (const float*)d_in[1];
    const float* task_info = (const float*)d_in[2];
    const float* h_real    = (const float*)d_in[3];
    const float* h_imag    = (const float*)d_in[4];

    const int B     = in_sizes[2] / 4;
    const int L     = in_sizes[0] / (B * 2);
    const int steps = (L - NFFT) / HOP + 1;
    const int G     = B * steps;

    hipMemsetAsync(d_out, 0, (size_t)out_size * sizeof(float), stream);

    eq_pbc_kernel<<<(G + 1) / 2, 256, 0, stream>>>(
        x_real, x_imag, task_info, h_real, h_imag, (float*)d_out, B, L, steps);
}

// Round 3
// 118.678 us; speedup vs baseline: 1.1539x; 1.1539x over previous
//
#include <hip/hip_runtime.h>
#include <math.h>

constexpr int NFFT = 256;
constexpr int HOP  = 216;
constexpr int PAD  = 20;
constexpr int LPW  = 296;            // padded intensity length
constexpr int IPS  = 308;            // IPAD row stride (mod 32 = 20: de-conflicts 2 frames/wave)

__device__ __forceinline__ void cmul(float& dr, float& di, float ar, float ai, float br, float bi) {
    dr = ar * br - ai * bi;
    di = ar * bi + ai * br;
}

// W16^m = (TC16[m], sgn*TS16[m]) = e^{sgn*i*2pi*m/16}; sgn=-1 fwd, +1 inv
constexpr float TC16[10] = {1.f, 0.92387953f, 0.70710678f, 0.38268343f, 0.f,
                            -0.38268343f, -0.70710678f, -0.92387953f, -1.f, -0.92387953f};
constexpr float TS16[10] = {0.f, 0.38268343f, 0.70710678f, 0.92387953f, 1.f,
                            0.92387953f, 0.70710678f, 0.38268343f, 0.f, -0.38268343f};

// In-register 16-point DFT: out[k] = sum_n in[n] * e^{SGN*i*2pi*n*k/16}.
// Natural order in and out. Fully unrolled, no memory ops.
template<int SGN>
__device__ __forceinline__ void fft16(float xr[16], float xi[16]) {
    constexpr float S = (float)SGN;
    float tr[4][4], ti[4][4];
    // stage 1: FFT-4 over n2 (elements n1, n1+4, n1+8, n1+12) -> t[n1][k2]
    #pragma unroll
    for (int n1 = 0; n1 < 4; ++n1) {
        float ar = xr[n1],      ai = xi[n1];
        float br = xr[n1 + 4],  bi = xi[n1 + 4];
        float cr = xr[n1 + 8],  ci = xi[n1 + 8];
        float dr = xr[n1 + 12], di = xi[n1 + 12];
        float Ar = ar + cr, Ai = ai + ci, Br = ar - cr, Bi = ai - ci;
        float Cr = br + dr, Ci = bi + di, Dr = br - dr, Di = bi - di;
        tr[n1][0] = Ar + Cr;      ti[n1][0] = Ai + Ci;
        tr[n1][2] = Ar - Cr;      ti[n1][2] = Ai - Ci;
        tr[n1][1] = Br - S * Di;  ti[n1][1] = Bi + S * Dr;
        tr[n1][3] = Br + S * Di;  ti[n1][3] = Bi - S * Dr;
    }
    // twiddle t[n1][k2] *= W16^{SGN*n1*k2}
    #pragma unroll
    for (int n1 = 1; n1 < 4; ++n1) {
        #pragma unroll
        for (int k2 = 1; k2 < 4; ++k2) {
            const int m = n1 * k2;
            const float wr = TC16[m], wi = S * TS16[m];
            float vr, vi;
            cmul(vr, vi, tr[n1][k2], ti[n1][k2], wr, wi);
            tr[n1][k2] = vr; ti[n1][k2] = vi;
        }
    }
    // stage 2: FFT-4 over n1 per k2 -> out[k2 + 4*k1]
    #pragma unroll
    for (int k2 = 0; k2 < 4; ++k2) {
        float ar = tr[0][k2], ai = ti[0][k2];
        float br = tr[1][k2], bi = ti[1][k2];
        float cr = tr[2][k2], ci = ti[2][k2];
        float dr = tr[3][k2], di = ti[3][k2];
        float Ar = ar + cr, Ai = ai + ci, Br = ar - cr, Bi = ai - ci;
        float Cr = br + dr, Ci = bi + di, Dr = br - dr, Di = bi - di;
        xr[k2]      = Ar + Cr;     xi[k2]      = Ai + Ci;
        xr[k2 + 8]  = Ar - Cr;     xi[k2 + 8]  = Ai - Ci;
        xr[k2 + 4]  = Br - S * Di; xi[k2 + 4]  = Bi + S * Dr;
        xr[k2 + 12] = Br + S * Di; xi[k2 + 12] = Bi - S * Dr;
    }
}

// Zero only the double-covered (overlap) stripes of the output:
// samples l = s*HOP + [0,40), s in [1,steps), all b/modes/components.
__global__ __launch_bounds__(128)
void zero_overlap(float* __restrict__ out, int B, int steps, int Lout) {
    const int s = blockIdx.x + 1;
    const int total = B * 160;
    for (int j = threadIdx.x; j < total; j += 128) {
        const int bb = j / 160;
        const int r  = j - bb * 160;
        out[((size_t)bb * Lout + (size_t)s * HOP - PAD) * 4 + r] = 0.0f;
    }
}

// Block = 256 threads = 8 frames x 2 modes x 16 threads.
// tid = fm*16 + i; fm = frame-local*2 + mode; i = lane within the FFT-16 group.
// SM float layout (aliased across barrier-separated phases):
//   TR [0..4351]    TI [4352..8703]        (transpose planes, 16 fm x 16x17)
//   IP  alias [0..4095]  (|X|^2 partials, 8 fr x 2 md x 256)
//   IPAD alias [4352..4352+8*308)          (padded intensity)
//   CR alias [0..2047], CI alias [2048..4095]  (FIR output c)
__global__ __launch_bounds__(256)
void eq_pbc_kernel(const float* __restrict__ x_real,
                   const float* __restrict__ x_imag,
                   const float* __restrict__ task_info,
                   const float* __restrict__ h_real,
                   const float* __restrict__ h_imag,
                   float* __restrict__ out,
                   int B, int L, int steps)
{
    __shared__ __align__(16) float SM[8704];

    const int tid = threadIdx.x;
    const int i   = tid & 15;
    const int fm  = tid >> 4;     // 0..15
    const int fr  = tid >> 5;     // frame-local 0..7
    const int md  = fm & 1;
    const int u   = tid & 31;

    const int G = B * steps;
    int g = blockIdx.x * 8 + fr;
    const bool valid = (g < G);
    if (!valid) g = G - 1;
    const int b  = g / steps;
    const int s  = g - b * steps;
    const int l0 = s * HOP;

    // base twiddle for W256^{i*k} (forward): e^{-2pi*i_lane/256}
    float sb, cb;
    __sincosf(-6.2831853071795864f * (1.0f / 256.0f) * (float)i, &sb, &cb);

    // ---- load: thread i holds x[l0 + i + 16*n2], its own mode ----
    float xr[16], xi[16];
    {
        const size_t base = ((size_t)b * L + l0) * 2 + (size_t)(2 * i + md);
        #pragma unroll
        for (int n2 = 0; n2 < 16; ++n2) {
            xr[n2] = x_real[base + 32 * n2];
            xi[n2] = x_imag[base + 32 * n2];
        }
    }

    // ---- forward step A: FFT-16 over n2 -> G[k2] ----
    fft16<-1>(xr, xi);

    // ---- twiddle G[k2] *= W256^{i*k2} (power tree) ----
    {
        float wr[16], wi[16];
        wr[1] = cb; wi[1] = sb;
        #pragma unroll
        for (int k = 2; k < 16; ++k) {
            const int h = k >> 1;
            cmul(wr[k], wi[k], wr[h], wi[h], wr[k - h], wi[k - h]);
        }
        #pragma unroll
        for (int k = 1; k < 16; ++k) {
            float vr, vi;
            cmul(vr, vi, xr[k], xi[k], wr[k], wi[k]);
            xr[k] = vr; xi[k] = vi;
        }
    }

    // ---- transpose (write row i, read column i) ----
    const int tb = fm * 272;   // 16*17 per fm plane
    #pragma unroll
    for (int k = 0; k < 16; ++k) {
        SM[tb + i * 17 + k]        = xr[k];
        SM[4352 + tb + i * 17 + k] = xi[k];
    }
    __syncthreads();                       // B1
    #pragma unroll
    for (int n1 = 0; n1 < 16; ++n1) {
        xr[n1] = SM[tb + n1 * 17 + i];
        xi[n1] = SM[4352 + tb + n1 * 17 + i];
    }

    // ---- forward step B: FFT-16 over n1 -> X[i + 16*k1] in reg k1 ----
    fft16<-1>(xr, xi);
    __syncthreads();                       // B2 (TR/TI dead; IP may be written)

    // ---- intensity partials IP[fr][md][f], f = i + 16*k1 ----
    #pragma unroll
    for (int k1 = 0; k1 < 16; ++k1)
        SM[fr * 512 + md * 256 + i + 16 * k1] = xr[k1] * xr[k1] + xi[k1] * xi[k1];
    __syncthreads();                       // B3

    // ---- combine modes + circular pad -> IPAD[fr][p], p=0..295 ----
    #pragma unroll
    for (int c = 0; c < 10; ++c) {
        const int p = u + 32 * c;
        if (p < LPW) {
            const int f = (p + 236) & 255;
            SM[4352 + fr * IPS + p] = SM[fr * 512 + f] + SM[fr * 512 + 256 + f];
        }
    }
    __syncthreads();                       // B4

    // ---- FIR: thread u of frame fr does outputs f0..f0+7, f0 = 8u ----
    {
        float W[48];
        #pragma unroll
        for (int c = 0; c < 12; ++c)
            *(float4*)&W[4 * c] = *(const float4*)&SM[4352 + fr * IPS + u * 8 + 4 * c];
        float phr[8], phi8[8];
        #pragma unroll
        for (int o = 0; o < 8; ++o) { phr[o] = 0.f; phi8[o] = 0.f; }
        #pragma unroll
        for (int t = 0; t < 41; ++t) {
            const float htr = h_real[t], hti = h_imag[t];
            #pragma unroll
            for (int o = 0; o < 8; ++o) {
                phr[o]  = fmaf(W[o + t], htr, phr[o]);
                phi8[o] = fmaf(W[o + t], hti, phi8[o]);
            }
        }
        const float P = exp2f(task_info[4 * b] * 0.33219280948873623f) * 0.5f;
        float4 cr0, cr1, ci0, ci1;
        cr0.x = 1.f - P * phi8[0]; cr0.y = 1.f - P * phi8[1]; cr0.z = 1.f - P * phi8[2]; cr0.w = 1.f - P * phi8[3];
        cr1.x = 1.f - P * phi8[4]; cr1.y = 1.f - P * phi8[5]; cr1.z = 1.f - P * phi8[6]; cr1.w = 1.f - P * phi8[7];
        ci0.x = P * phr[0]; ci0.y = P * phr[1]; ci0.z = P * phr[2]; ci0.w = P * phr[3];
        ci1.x = P * phr[4]; ci1.y = P * phr[5]; ci1.z = P * phr[6]; ci1.w = P * phr[7];
        *(float4*)&SM[fr * 256 + u * 8]          = cr0;
        *(float4*)&SM[fr * 256 + u * 8 + 4]      = cr1;
        *(float4*)&SM[2048 + fr * 256 + u * 8]     = ci0;
        *(float4*)&SM[2048 + fr * 256 + u * 8 + 4] = ci1;
    }
    __syncthreads();                       // B5

    // ---- modulate X[f] *= c[f], f = i + 16*k1 ----
    #pragma unroll
    for (int k1 = 0; k1 < 16; ++k1) {
        const float cr_ = SM[fr * 256 + i + 16 * k1];
        const float ci_ = SM[2048 + fr * 256 + i + 16 * k1];
        const float vr = xr[k1] * cr_ - xi[k1] * ci_;
        const float vi = xr[k1] * ci_ + xi[k1] * cr_;
        xr[k1] = vr; xi[k1] = vi;
    }

    // ---- inverse step A: IFFT-16 over k1 -> V[n1]; twiddle conj ----
    fft16<1>(xr, xi);
    {
        float wr[16], wi[16];
        wr[1] = cb; wi[1] = -sb;           // conj base
        #pragma unroll
        for (int k = 2; k < 16; ++k) {
            const int h = k >> 1;
            cmul(wr[k], wi[k], wr[h], wi[h], wr[k - h], wi[k - h]);
        }
        #pragma unroll
        for (int k = 1; k < 16; ++k) {
            float vr, vi;
            cmul(vr, vi, xr[k], xi[k], wr[k], wi[k]);
            xr[k] = vr; xi[k] = vi;
        }
    }
    __syncthreads();                       // B6 (CR/CI + IPAD dead; TR/TI reused)

    // ---- inverse transpose ----
    #pragma unroll
    for (int k = 0; k < 16; ++k) {
        SM[tb + i * 17 + k]        = xr[k];
        SM[4352 + tb + i * 17 + k] = xi[k];
    }
    __syncthreads();                       // B7
    #pragma unroll
    for (int k2 = 0; k2 < 16; ++k2) {
        xr[k2] = SM[tb + k2 * 17 + i];
        xi[k2] = SM[4352 + tb + k2 * 17 + i];
    }

    // ---- inverse step B: IFFT-16 over k2 -> y[i + 16*n2] (x256) ----
    fft16<1>(xr, xi);

    // ---- OLA + wsum + crop ----
    if (valid) {
        const int Lout = L - 2 * PAD;
        float* obase = out + (size_t)b * Lout * 4 + md * 2;
        #pragma unroll
        for (int n2 = 0; n2 < 16; ++n2) {
            const int n  = i + 16 * n2;
            const int la = l0 + n;
            if (la < PAD || la >= L - PAD) continue;
            const bool ov = (n < NFFT - HOP && s > 0) || (n >= HOP && s + 1 < steps);
            const float sc = (ov ? 0.5f : 1.0f) * (1.0f / 256.0f);
            float* p = obase + (size_t)(la - PAD) * 4;
            const float vr = xr[n2] * sc, vi = xi[n2] * sc;
            if (ov) { atomicAdd(p, vr); atomicAdd(p + 1, vi); }
            else    { *(float2*)p = make_float2(vr, vi); }
        }
    }
}

extern "C" void kernel_launch(void* const* d_in, const int* in_sizes, int n_in,
                              void* d_out, int out_size, void* d_ws, size_t ws_size,
                              hipStream_t stream) {
    const float* x_real    = (const float*)d_in[0];
    const float* x_imag    = (const float*)d_in[1];
    const float* task_info = (const float*)d_in[2];
    const float* h_real    = (const float*)d_in[3];
    const float* h_imag    = (const float*)d_in[4];

    const int B     = in_sizes[2] / 4;
    const int L     = in_sizes[0] / (B * 2);
    const int steps = (L - NFFT) / HOP + 1;
    const int G     = B * steps;
    const int Lout  = L - 2 * PAD;

    // Zero only the overlap stripes (replaces full-output memset).
    if (steps > 1)
        zero_overlap<<<steps - 1, 128, 0, stream>>>((float*)d_out, B, steps, Lout);

    eq_pbc_kernel<<<(G + 7) / 8, 256, 0, stream>>>(
        x_real, x_imag, task_info, h_real, h_imag, (float*)d_out, B, L, steps);
}